// Round 12
// baseline (1003.121 us; speedup 1.0000x reference)
//
#include <hip/hip_runtime.h>
#include <hip/hip_bf16.h>
#include <hip/hip_fp8.h>

#define N_ROWS 8192
#define DIM    1024
#define NCLS   10240
#define S_SCALE 30.0f
#define M_LARGE 0.4f
#define M_SMALL 0.1f

typedef __attribute__((ext_vector_type(8))) int   i32x8;
typedef __attribute__((ext_vector_type(4))) int   i32x4;
typedef __attribute__((ext_vector_type(4))) float f32x4;

__device__ __forceinline__ unsigned char f2q(float f){
    __hip_fp8_e4m3 q(f);                      // OCP e4m3fn (gfx950 format)
    return *reinterpret_cast<unsigned char*>(&q);
}

#define GLD16(gp, lp) __builtin_amdgcn_global_load_lds( \
    (const __attribute__((address_space(1))) unsigned int*)(gp), \
    (__attribute__((address_space(3))) unsigned int*)(lp), 16, 0, 0)

// ---- prep: inv L2 norms + raw f32->fp8(e4m3) conversion, zero gsum ----
__global__ void prep_kernel(const float* __restrict__ x, const float* __restrict__ w,
                            float* __restrict__ inv_x, float* __restrict__ inv_w,
                            float* __restrict__ gsum,
                            unsigned char* __restrict__ xq, unsigned char* __restrict__ wq){
    int b = blockIdx.x;
    bool isx = (b < N_ROWS);
    int r = isx ? b : b - N_ROWS;
    const float4* src = (const float4*)((isx ? x : w) + (size_t)r * DIM);
    float4 v = src[threadIdx.x];                      // 256 threads * 4 = 1024
    uchar4 pk;
    pk.x = f2q(v.x); pk.y = f2q(v.y); pk.z = f2q(v.z); pk.w = f2q(v.w);
    ((uchar4*)((isx ? xq : wq) + (size_t)r * DIM))[threadIdx.x] = pk;
    float ss = v.x*v.x + v.y*v.y + v.z*v.z + v.w*v.w;
    #pragma unroll
    for (int o = 32; o; o >>= 1) ss += __shfl_down(ss, o);
    __shared__ float part[4];
    int lane = threadIdx.x & 63, wid = threadIdx.x >> 6;
    if (lane == 0) part[wid] = ss;
    __syncthreads();
    if (threadIdx.x == 0){
        float t = part[0] + part[1] + part[2] + part[3];
        float inv = 1.0f / fmaxf(sqrtf(t), 1e-12f);
        if (isx){ inv_x[r] = inv; gsum[r] = 0.0f; }
        else      inv_w[r] = inv;
    }
}

// ---- target logit: exact f32 dot x_i . w_label (decoupled from fp8 GEMM) ----
__global__ void target_kernel(const float* __restrict__ x, const float* __restrict__ w,
                              const int* __restrict__ labels,
                              const float* __restrict__ inv_x, const float* __restrict__ inv_w,
                              float* __restrict__ tgt){
    int wid = threadIdx.x >> 6, lane = threadIdx.x & 63;
    int i = blockIdx.x * 4 + wid;
    int lab = labels[i];
    const float4* xp = (const float4*)(x + (size_t)i   * DIM);
    const float4* wp = (const float4*)(w + (size_t)lab * DIM);
    float acc = 0.f;
    #pragma unroll
    for (int c = 0; c < 4; ++c){
        float4 a = xp[c*64 + lane];
        float4 b = wp[c*64 + lane];
        acc += a.x*b.x + a.y*b.y + a.z*b.z + a.w*b.w;
    }
    #pragma unroll
    for (int o = 32; o; o >>= 1) acc += __shfl_down(acc, o);
    if (lane == 0){
        float c = acc * inv_x[i] * inv_w[lab];
        c = fminf(fmaxf(c, -1.f), 1.f);
        tgt[i] = c;
    }
}

// ---- fused MX-fp8 GEMM: m97/m148 structure — 128x128 tile, K-tile=128B,
// 4 waves, double-buffered LDS, one barrier per K-tile, NO launch_bounds ----
#define BM 128
#define BN 128
#define BKB 128              // fp8 bytes per K-tile
#define NT (DIM/BKB)         // 8
#define GRID_X (NCLS/BN)     // 80
#define GRID_Y (N_ROWS/BM)   // 64
#define NWG (GRID_X*GRID_Y)  // 5120, % 8 == 0

// stage one 128x128B tile = 4 x GLD16 (each 256thr x 16B = 32 rows)
#define STAGE(dst, gsrc, KO) { \
    GLD16(gsrc + (KO),                  &(dst)[ldso]); \
    GLD16(gsrc + (size_t)32*DIM + (KO), &(dst)[32*BKB + ldso]); \
    GLD16(gsrc + (size_t)64*DIM + (KO), &(dst)[64*BKB + ldso]); \
    GLD16(gsrc + (size_t)96*DIM + (KO), &(dst)[96*BKB + ldso]); }

__global__ void gemm_kernel(
        const unsigned char* __restrict__ xq, const unsigned char* __restrict__ wq,
        const float* __restrict__ inv_x, const float* __restrict__ inv_w,
        float* __restrict__ gsum){
    __shared__ __align__(16) unsigned char As[2][BM*BKB];   // 2 x 16 KB
    __shared__ __align__(16) unsigned char Bs[2][BN*BKB];   // 2 x 16 KB
    __shared__ float sumrow[BM];

    int tid = threadIdx.x;
    int bid = blockIdx.x;
    // bijective XCD swizzle
    int swz = (bid & 7) * (NWG/8) + (bid >> 3);
    int by = swz / GRID_X, bx = swz % GRID_X;
    int row0 = by * BM, col0 = bx * BN;
    int wid = tid >> 6, lane = tid & 63;
    int wm = wid >> 1, wn = wid & 1;           // 2x2 waves; wave owns 64x64
    int g = lane >> 4, l16 = lane & 15;

    if (tid < BM) sumrow[tid] = 0.f;

    // staging geometry: one GLD16 = 256 thr x 16B = 32 rows x 128 B
    int srow = tid >> 3;                       // 0..31
    int csrc = (tid & 7) ^ (srow & 7);         // pre-swizzled source chunk (16B units)
    const unsigned char* gA = xq + (size_t)(row0 + srow) * DIM + csrc * 16;
    const unsigned char* gB = wq + (size_t)(col0 + srow) * DIM + csrc * 16;
    int ldso = srow * BKB + (tid & 7) * 16;    // linear LDS dest (bytes)

    f32x4 acc[4][4] = {};

    // prologue: stage tile 0
    STAGE(As[0], gA, 0);
    STAGE(Bs[0], gB, 0);
    __syncthreads();                            // drains vmcnt before barrier

    for (int kt = 0; kt < NT; ++kt){
        int b = kt & 1, nb = b ^ 1;
        if (kt + 1 < NT){
            int kn = (kt + 1) * BKB;
            STAGE(As[nb], gA, kn);
            STAGE(Bs[nb], gB, kn);
        }

        // B fragments: lane (g,l16) holds k-bytes [32g,32g+32) of its row,
        // at physical 16B chunks (2g)^(r&7), (2g+1)^(r&7)  -> 2-way banking (free)
        i32x8 bf[4];
        #pragma unroll
        for (int ni = 0; ni < 4; ++ni){
            int r = wn*64 + ni*16 + l16;
            int base = r * BKB, sw = (r & 7) << 4;
            i32x4 lo = *(const i32x4*)&Bs[b][base + ((g*32     ) ^ sw)];
            i32x4 hi = *(const i32x4*)&Bs[b][base + ((g*32 + 16) ^ sw)];
            bf[ni] = __builtin_shufflevector(lo, hi, 0,1,2,3,4,5,6,7);
        }
        // A fragments one-at-a-time, consumed immediately (peak tuple liveness:
        // bf[4] + one af = 40 regs, not 64)
        #pragma unroll
        for (int mi = 0; mi < 4; ++mi){
            int r = wm*64 + mi*16 + l16;
            int base = r * BKB, sw = (r & 7) << 4;
            i32x4 lo = *(const i32x4*)&As[b][base + ((g*32     ) ^ sw)];
            i32x4 hi = *(const i32x4*)&As[b][base + ((g*32 + 16) ^ sw)];
            i32x8 af = __builtin_shufflevector(lo, hi, 0,1,2,3,4,5,6,7);
            #pragma unroll
            for (int ni = 0; ni < 4; ++ni)
                acc[mi][ni] = __builtin_amdgcn_mfma_scale_f32_16x16x128_f8f6f4(
                    af, bf[ni], acc[mi][ni], 0, 0, 0, 0x7F7F7F7F, 0, 0x7F7F7F7F);
        }

        __syncthreads();   // reads of b done; vmcnt drained -> nb ready
    }

    // epilogue: scale by inv_x[i]*inv_w[j], clamp, exp(S*.), row-sum
    // C/D layout (16x16 shape-determined): col=lane&15, row=g*4+rg
    float iw[4];
    #pragma unroll
    for (int n = 0; n < 4; ++n) iw[n] = inv_w[col0 + wn*64 + n*16 + l16];
    #pragma unroll
    for (int m = 0; m < 4; ++m){
        #pragma unroll
        for (int rg = 0; rg < 4; ++rg){
            int rl = wm*64 + m*16 + g*4 + rg;        // local row of this value
            float ix = inv_x[row0 + rl];
            float v = 0.f;
            #pragma unroll
            for (int n = 0; n < 4; ++n){
                float c = acc[m][n][rg] * ix * iw[n];
                c = fminf(fmaxf(c, -1.f), 1.f);
                v += __expf(S_SCALE * c);
            }
            v += __shfl_xor(v, 1);
            v += __shfl_xor(v, 2);
            v += __shfl_xor(v, 4);
            v += __shfl_xor(v, 8);
            if (l16 == 0) atomicAdd(&sumrow[rl], v);
        }
    }
    __syncthreads();
    if (tid < BM) atomicAdd(&gsum[row0 + tid], sumrow[tid]);
}

// ---------------- finalize: per-row loss, mean ----------------
__global__ void finalize_kernel(const float* __restrict__ tgt, const float* __restrict__ gsum,
                                const int* __restrict__ labels, float* __restrict__ out){
    double local = 0.0;
    for (int i = threadIdx.x; i < N_ROWS; i += 256){
        float tv = tgt[i];
        float m  = (labels[i] <= 5) ? M_LARGE : M_SMALL;
        float numer = S_SCALE * (tv - m);
        float excl  = gsum[i] - __expf(S_SCALE * tv);
        float denom = __expf(numer) + excl;
        float L = numer - logf(denom);
        local += (double)L;
    }
    #pragma unroll
    for (int o = 32; o; o >>= 1) local += __shfl_down(local, o);
    __shared__ double part[4];
    int lane = threadIdx.x & 63, wid = threadIdx.x >> 6;
    if (lane == 0) part[wid] = local;
    __syncthreads();
    if (threadIdx.x == 0){
        double s = part[0] + part[1] + part[2] + part[3];
        out[0] = (float)(-s / (double)N_ROWS);
    }
}

extern "C" void kernel_launch(void* const* d_in, const int* in_sizes, int n_in,
                              void* d_out, int out_size, void* d_ws, size_t ws_size,
                              hipStream_t stream) {
    const float* x      = (const float*)d_in[0];
    const int*   labels = (const int*)  d_in[1];
    const float* w      = (const float*)d_in[2];

    float* ws    = (float*)d_ws;
    float* inv_x = ws;                    // N
    float* inv_w = inv_x + N_ROWS;        // C
    float* tgt   = inv_w + NCLS;          // N
    float* gsum  = tgt   + N_ROWS;        // N
    unsigned char* xq = (unsigned char*)(gsum + N_ROWS);  // N*D fp8
    unsigned char* wq = xq + (size_t)N_ROWS * DIM;        // C*D fp8

    prep_kernel<<<N_ROWS + NCLS, 256, 0, stream>>>(x, w, inv_x, inv_w, gsum, xq, wq);
    target_kernel<<<N_ROWS/4, 256, 0, stream>>>(x, w, labels, inv_x, inv_w, tgt);
    gemm_kernel<<<NWG, 256, 0, stream>>>(xq, wq, inv_x, inv_w, gsum);
    finalize_kernel<<<1, 256, 0, stream>>>(tgt, gsum, labels, (float*)d_out);
}

// Round 13
// 163.088 us; speedup vs baseline: 6.1508x; 6.1508x over previous
//
#include <hip/hip_runtime.h>
#include <hip/hip_bf16.h>

#define N_ROWS 8192
#define DIM    1024
#define NCLS   10240
#define S_SCALE 30.0f
#define M_LARGE 0.4f
#define M_SMALL 0.1f

typedef __attribute__((ext_vector_type(4))) int   i32x4;

#define GLD16(gp, lp) __builtin_amdgcn_global_load_lds( \
    (const __attribute__((address_space(1))) unsigned int*)(gp), \
    (__attribute__((address_space(3))) unsigned int*)(lp), 16, 0, 0)

// ---- prep: inv L2 norms + per-row symmetric int8 quantization, zero gsum ----
// fx[i] = (amax_x[i]/127) * inv_x[i]; cosine = acc_int * fx[i] * fw[j]
__global__ void prep_kernel(const float* __restrict__ x, const float* __restrict__ w,
                            float* __restrict__ inv_x, float* __restrict__ inv_w,
                            float* __restrict__ fx, float* __restrict__ fw,
                            float* __restrict__ gsum,
                            signed char* __restrict__ xq, signed char* __restrict__ wq){
    int b = blockIdx.x;
    bool isx = (b < N_ROWS);
    int r = isx ? b : b - N_ROWS;
    const float4* src = (const float4*)((isx ? x : w) + (size_t)r * DIM);
    float4 v = src[threadIdx.x];                      // 256 threads * 4 = 1024
    float ss = v.x*v.x + v.y*v.y + v.z*v.z + v.w*v.w;
    float am = fmaxf(fmaxf(fabsf(v.x), fabsf(v.y)), fmaxf(fabsf(v.z), fabsf(v.w)));
    #pragma unroll
    for (int o = 32; o; o >>= 1){
        ss += __shfl_down(ss, o);
        am  = fmaxf(am, __shfl_down(am, o));
    }
    __shared__ float pss[4], pam[4];
    int lane = threadIdx.x & 63, wid = threadIdx.x >> 6;
    if (lane == 0){ pss[wid] = ss; pam[wid] = am; }
    __syncthreads();
    float t    = pss[0] + pss[1] + pss[2] + pss[3];
    float amax = fmaxf(fmaxf(pam[0], pam[1]), fmaxf(pam[2], pam[3]));
    float inv  = 1.0f / fmaxf(sqrtf(t), 1e-12f);
    float s    = fmaxf(amax, 1e-20f) * (1.0f/127.0f);
    float rs   = 127.0f / fmaxf(amax, 1e-20f);
    int q0 = __float2int_rn(v.x * rs), q1 = __float2int_rn(v.y * rs);
    int q2 = __float2int_rn(v.z * rs), q3 = __float2int_rn(v.w * rs);
    unsigned int pk = (q0 & 0xff) | ((q1 & 0xff) << 8) | ((q2 & 0xff) << 16) | ((q3 & 0xff) << 24);
    ((unsigned int*)((isx ? xq : wq) + (size_t)r * DIM))[threadIdx.x] = pk;
    if (threadIdx.x == 0){
        if (isx){ inv_x[r] = inv; fx[r] = s * inv; gsum[r] = 0.0f; }
        else    { inv_w[r] = inv; fw[r] = s * inv; }
    }
}

// ---- target logit: exact f32 dot x_i . w_label (decoupled from i8 GEMM) ----
__global__ void target_kernel(const float* __restrict__ x, const float* __restrict__ w,
                              const int* __restrict__ labels,
                              const float* __restrict__ inv_x, const float* __restrict__ inv_w,
                              float* __restrict__ tgt){
    int wid = threadIdx.x >> 6, lane = threadIdx.x & 63;
    int i = blockIdx.x * 4 + wid;
    int lab = labels[i];
    const float4* xp = (const float4*)(x + (size_t)i   * DIM);
    const float4* wp = (const float4*)(w + (size_t)lab * DIM);
    float acc = 0.f;
    #pragma unroll
    for (int c = 0; c < 4; ++c){
        float4 a = xp[c*64 + lane];
        float4 b = wp[c*64 + lane];
        acc += a.x*b.x + a.y*b.y + a.z*b.z + a.w*b.w;
    }
    #pragma unroll
    for (int o = 32; o; o >>= 1) acc += __shfl_down(acc, o);
    if (lane == 0){
        float c = acc * inv_x[i] * inv_w[lab];
        c = fminf(fmaxf(c, -1.f), 1.f);
        tgt[i] = c;
    }
}

// ---- fused i8 GEMM: R4 champion structure, dtype-swapped. 256x256 tile,
// K-tile=128 i8 (128B rows, proven 0-conflict swizzle), 4-phase, NT=8 ----
#define BM 256
#define BN 256
#define BKB 128              // i8 elems (bytes) per K-tile
#define NT (DIM/BKB)         // 8
#define GRID_X (NCLS/BN)     // 40
#define GRID_Y (N_ROWS/BM)   // 32
#define NWG (GRID_X*GRID_Y)  // 1280, % 8 == 0

__global__ __launch_bounds__(512, 2) void gemm_kernel(
        const signed char* __restrict__ xq, const signed char* __restrict__ wq,
        const float* __restrict__ fx, const float* __restrict__ fw,
        float* __restrict__ gsum){
    __shared__ __align__(16) unsigned char As[2][BM*BKB];   // 2 x 32 KB
    __shared__ __align__(16) unsigned char Bs[2][BN*BKB];   // 2 x 32 KB
    __shared__ float sumrow[BM];

    int tid = threadIdx.x;
    int bid = blockIdx.x;
    // bijective XCD swizzle
    int swz = (bid & 7) * (NWG/8) + (bid >> 3);
    int by = swz / GRID_X, bx = swz % GRID_X;
    int row0 = by * BM, col0 = bx * BN;
    int wid = tid >> 6, lane = tid & 63;
    int wm = wid >> 2, wn = wid & 3;           // 2M x 4N wave grid; wave owns 128x64
    int g = lane >> 4, l16 = lane & 15;

    if (tid < BM) sumrow[tid] = 0.f;

    // staging geometry: one GLD16 = 512 thr x 16B = 64 rows x 128 B
    int srow = tid >> 3;                       // 0..63
    int csrc = (tid & 7) ^ (srow & 7);         // pre-swizzled source chunk (16B units)
    const signed char* gA = xq + (size_t)(row0 + srow) * DIM + csrc * 16;
    const signed char* gB = wq + (size_t)(col0 + srow) * DIM + csrc * 16;
    int ldso = srow * BKB + (tid & 7) * 16;    // linear LDS dest (bytes)

    i32x4 acc[8][4] = {};

    // prologue: stage tile 0 fully
    #pragma unroll
    for (int h = 0; h < 4; ++h){
        GLD16(gA + (size_t)(h*64)*DIM, &As[0][h*64*BKB + ldso]);
        GLD16(gB + (size_t)(h*64)*DIM, &Bs[0][h*64*BKB + ldso]);
    }
    asm volatile("s_waitcnt vmcnt(0)" ::: "memory");
    __builtin_amdgcn_s_barrier();

    for (int kt = 0; kt < NT; ++kt){
        int b = kt & 1, nb = b ^ 1;
        int knext = (kt + 1) * BKB;
        bool pre = (kt + 1 < NT);
        i32x4 af[4], bfv[4];

        // ---- P0: read A m0-3 k0 + B n0-3 k0 ; stage next A rows 0-127
        #pragma unroll
        for (int m = 0; m < 4; ++m){
            int r = wm*128 + m*16 + l16;
            af[m] = *(const i32x4*)&As[b][r*BKB + ((g ^ (r & 7)) << 4)];
        }
        #pragma unroll
        for (int n = 0; n < 4; ++n){
            int r = wn*64 + n*16 + l16;
            bfv[n] = *(const i32x4*)&Bs[b][r*BKB + ((g ^ (r & 7)) << 4)];
        }
        if (pre){
            GLD16(gA + knext,                    &As[nb][ldso]);
            GLD16(gA + knext + (size_t)64*DIM,   &As[nb][64*BKB + ldso]);
        }
        __builtin_amdgcn_s_barrier();
        asm volatile("s_waitcnt lgkmcnt(0)" ::: "memory");
        __builtin_amdgcn_sched_barrier(0);
        __builtin_amdgcn_s_setprio(1);
        #pragma unroll
        for (int m = 0; m < 4; ++m)
            #pragma unroll
            for (int n = 0; n < 4; ++n)
                acc[m][n] = __builtin_amdgcn_mfma_i32_16x16x64_i8(af[m], bfv[n], acc[m][n], 0, 0, 0);
        __builtin_amdgcn_s_setprio(0);
        __builtin_amdgcn_s_barrier();

        // ---- P1: read A m4-7 k0 ; stage next A rows 128-255 ; reuse B k0 regs
        #pragma unroll
        for (int m = 0; m < 4; ++m){
            int r = wm*128 + (m+4)*16 + l16;
            af[m] = *(const i32x4*)&As[b][r*BKB + ((g ^ (r & 7)) << 4)];
        }
        if (pre){
            GLD16(gA + knext + (size_t)128*DIM,  &As[nb][128*BKB + ldso]);
            GLD16(gA + knext + (size_t)192*DIM,  &As[nb][192*BKB + ldso]);
        }
        __builtin_amdgcn_s_barrier();
        asm volatile("s_waitcnt lgkmcnt(0)" ::: "memory");
        __builtin_amdgcn_sched_barrier(0);
        __builtin_amdgcn_s_setprio(1);
        #pragma unroll
        for (int m = 0; m < 4; ++m)
            #pragma unroll
            for (int n = 0; n < 4; ++n)
                acc[m+4][n] = __builtin_amdgcn_mfma_i32_16x16x64_i8(af[m], bfv[n], acc[m+4][n], 0, 0, 0);
        __builtin_amdgcn_s_setprio(0);
        __builtin_amdgcn_s_barrier();

        // ---- P2: read A m0-3 k1 + B n0-3 k1 ; stage next B rows 0-127
        #pragma unroll
        for (int m = 0; m < 4; ++m){
            int r = wm*128 + m*16 + l16;
            af[m] = *(const i32x4*)&As[b][r*BKB + (((4+g) ^ (r & 7)) << 4)];
        }
        #pragma unroll
        for (int n = 0; n < 4; ++n){
            int r = wn*64 + n*16 + l16;
            bfv[n] = *(const i32x4*)&Bs[b][r*BKB + (((4+g) ^ (r & 7)) << 4)];
        }
        if (pre){
            GLD16(gB + knext,                    &Bs[nb][ldso]);
            GLD16(gB + knext + (size_t)64*DIM,   &Bs[nb][64*BKB + ldso]);
        }
        __builtin_amdgcn_s_barrier();
        asm volatile("s_waitcnt lgkmcnt(0)" ::: "memory");
        __builtin_amdgcn_sched_barrier(0);
        __builtin_amdgcn_s_setprio(1);
        #pragma unroll
        for (int m = 0; m < 4; ++m)
            #pragma unroll
            for (int n = 0; n < 4; ++n)
                acc[m][n] = __builtin_amdgcn_mfma_i32_16x16x64_i8(af[m], bfv[n], acc[m][n], 0, 0, 0);
        __builtin_amdgcn_s_setprio(0);
        __builtin_amdgcn_s_barrier();

        // ---- P3: read A m4-7 k1 ; stage next B rows 128-255
        #pragma unroll
        for (int m = 0; m < 4; ++m){
            int r = wm*128 + (m+4)*16 + l16;
            af[m] = *(const i32x4*)&As[b][r*BKB + (((4+g) ^ (r & 7)) << 4)];
        }
        if (pre){
            GLD16(gB + knext + (size_t)128*DIM,  &Bs[nb][128*BKB + ldso]);
            GLD16(gB + knext + (size_t)192*DIM,  &Bs[nb][192*BKB + ldso]);
        }
        __builtin_amdgcn_s_barrier();
        asm volatile("s_waitcnt lgkmcnt(0)" ::: "memory");
        __builtin_amdgcn_sched_barrier(0);
        __builtin_amdgcn_s_setprio(1);
        #pragma unroll
        for (int m = 0; m < 4; ++m)
            #pragma unroll
            for (int n = 0; n < 4; ++n)
                acc[m+4][n] = __builtin_amdgcn_mfma_i32_16x16x64_i8(af[m], bfv[n], acc[m+4][n], 0, 0, 0);
        __builtin_amdgcn_s_setprio(0);

        // ---- K-tile boundary (R4-proven): stages are 1-4 phases old
        asm volatile("s_waitcnt vmcnt(0)" ::: "memory");
        __builtin_amdgcn_sched_barrier(0);
        __builtin_amdgcn_s_barrier();
    }

    // epilogue: cosine = acc * fx[i] * fw[j]; clamp, exp(S*.), row-sum
    // C/D layout (16x16, dtype-independent): col=lane&15, row=g*4+rg
    float fwv[4];
    #pragma unroll
    for (int n = 0; n < 4; ++n) fwv[n] = fw[col0 + wn*64 + n*16 + l16];
    #pragma unroll
    for (int m = 0; m < 8; ++m){
        #pragma unroll
        for (int rg = 0; rg < 4; ++rg){
            int rl = wm*128 + m*16 + g*4 + rg;       // local row of this value
            float fxr = fx[row0 + rl];
            float v = 0.f;
            #pragma unroll
            for (int n = 0; n < 4; ++n){
                float c = (float)acc[m][n][rg] * fxr * fwv[n];
                c = fminf(fmaxf(c, -1.f), 1.f);
                v += __expf(S_SCALE * c);
            }
            v += __shfl_xor(v, 1);
            v += __shfl_xor(v, 2);
            v += __shfl_xor(v, 4);
            v += __shfl_xor(v, 8);
            if (l16 == 0) atomicAdd(&sumrow[rl], v);
        }
    }
    __syncthreads();
    if (tid < BM) atomicAdd(&gsum[row0 + tid], sumrow[tid]);
}

// ---------------- finalize: per-row loss, mean ----------------
__global__ void finalize_kernel(const float* __restrict__ tgt, const float* __restrict__ gsum,
                                const int* __restrict__ labels, float* __restrict__ out){
    double local = 0.0;
    for (int i = threadIdx.x; i < N_ROWS; i += 256){
        float tv = tgt[i];
        float m  = (labels[i] <= 5) ? M_LARGE : M_SMALL;
        float numer = S_SCALE * (tv - m);
        float excl  = gsum[i] - __expf(S_SCALE * tv);
        float denom = __expf(numer) + excl;
        float L = numer - logf(denom);
        local += (double)L;
    }
    #pragma unroll
    for (int o = 32; o; o >>= 1) local += __shfl_down(local, o);
    __shared__ double part[4];
    int lane = threadIdx.x & 63, wid = threadIdx.x >> 6;
    if (lane == 0) part[wid] = local;
    __syncthreads();
    if (threadIdx.x == 0){
        double s = part[0] + part[1] + part[2] + part[3];
        out[0] = (float)(-s / (double)N_ROWS);
    }
}

extern "C" void kernel_launch(void* const* d_in, const int* in_sizes, int n_in,
                              void* d_out, int out_size, void* d_ws, size_t ws_size,
                              hipStream_t stream) {
    const float* x      = (const float*)d_in[0];
    const int*   labels = (const int*)  d_in[1];
    const float* w      = (const float*)d_in[2];

    float* ws    = (float*)d_ws;
    float* inv_x = ws;                    // N
    float* inv_w = inv_x + N_ROWS;        // C
    float* fx    = inv_w + NCLS;          // N
    float* fw    = fx    + N_ROWS;        // C
    float* tgt   = fw    + NCLS;          // N
    float* gsum  = tgt   + N_ROWS;        // N
    signed char* xq = (signed char*)(gsum + N_ROWS);   // N*D i8
    signed char* wq = xq + (size_t)N_ROWS * DIM;       // C*D i8

    prep_kernel<<<N_ROWS + NCLS, 256, 0, stream>>>(x, w, inv_x, inv_w, fx, fw, gsum, xq, wq);
    target_kernel<<<N_ROWS/4, 256, 0, stream>>>(x, w, labels, inv_x, inv_w, tgt);
    gemm_kernel<<<NWG, 512, 0, stream>>>(xq, wq, fx, fw, gsum);
    finalize_kernel<<<1, 256, 0, stream>>>(tgt, gsum, labels, (float*)d_out);
}

// Round 14
// 153.200 us; speedup vs baseline: 6.5478x; 1.0645x over previous
//
#include <hip/hip_runtime.h>
#include <hip/hip_bf16.h>

#define N_ROWS 8192
#define DIM    1024
#define NCLS   10240
#define S_SCALE 30.0f
#define M_LARGE 0.4f
#define M_SMALL 0.1f

typedef __attribute__((ext_vector_type(4))) int   i32x4;

#define GLD16(gp, lp) __builtin_amdgcn_global_load_lds( \
    (const __attribute__((address_space(1))) unsigned int*)(gp), \
    (__attribute__((address_space(3))) unsigned int*)(lp), 16, 0, 0)

// ---- prep: inv L2 norms + per-row symmetric int8 quantization, zero gsum ----
__global__ void prep_kernel(const float* __restrict__ x, const float* __restrict__ w,
                            float* __restrict__ inv_x, float* __restrict__ inv_w,
                            float* __restrict__ fx, float* __restrict__ fw,
                            float* __restrict__ gsum,
                            signed char* __restrict__ xq, signed char* __restrict__ wq){
    int b = blockIdx.x;
    bool isx = (b < N_ROWS);
    int r = isx ? b : b - N_ROWS;
    const float4* src = (const float4*)((isx ? x : w) + (size_t)r * DIM);
    float4 v = src[threadIdx.x];                      // 256 threads * 4 = 1024
    float ss = v.x*v.x + v.y*v.y + v.z*v.z + v.w*v.w;
    float am = fmaxf(fmaxf(fabsf(v.x), fabsf(v.y)), fmaxf(fabsf(v.z), fabsf(v.w)));
    #pragma unroll
    for (int o = 32; o; o >>= 1){
        ss += __shfl_down(ss, o);
        am  = fmaxf(am, __shfl_down(am, o));
    }
    __shared__ float pss[4], pam[4];
    int lane = threadIdx.x & 63, wid = threadIdx.x >> 6;
    if (lane == 0){ pss[wid] = ss; pam[wid] = am; }
    __syncthreads();
    float t    = pss[0] + pss[1] + pss[2] + pss[3];
    float amax = fmaxf(fmaxf(pam[0], pam[1]), fmaxf(pam[2], pam[3]));
    float inv  = 1.0f / fmaxf(sqrtf(t), 1e-12f);
    float s    = fmaxf(amax, 1e-20f) * (1.0f/127.0f);
    float rs   = 127.0f / fmaxf(amax, 1e-20f);
    int q0 = __float2int_rn(v.x * rs), q1 = __float2int_rn(v.y * rs);
    int q2 = __float2int_rn(v.z * rs), q3 = __float2int_rn(v.w * rs);
    unsigned int pk = (q0 & 0xff) | ((q1 & 0xff) << 8) | ((q2 & 0xff) << 16) | ((q3 & 0xff) << 24);
    ((unsigned int*)((isx ? xq : wq) + (size_t)r * DIM))[threadIdx.x] = pk;
    if (threadIdx.x == 0){
        if (isx){ inv_x[r] = inv; fx[r] = s * inv; gsum[r] = 0.0f; }
        else    { inv_w[r] = inv; fw[r] = s * inv; }
    }
}

// ---- target logit: exact f32 dot x_i . w_label (decoupled from i8 GEMM) ----
__global__ void target_kernel(const float* __restrict__ x, const float* __restrict__ w,
                              const int* __restrict__ labels,
                              const float* __restrict__ inv_x, const float* __restrict__ inv_w,
                              float* __restrict__ tgt){
    int wid = threadIdx.x >> 6, lane = threadIdx.x & 63;
    int i = blockIdx.x * 4 + wid;
    int lab = labels[i];
    const float4* xp = (const float4*)(x + (size_t)i   * DIM);
    const float4* wp = (const float4*)(w + (size_t)lab * DIM);
    float acc = 0.f;
    #pragma unroll
    for (int c = 0; c < 4; ++c){
        float4 a = xp[c*64 + lane];
        float4 b = wp[c*64 + lane];
        acc += a.x*b.x + a.y*b.y + a.z*b.z + a.w*b.w;
    }
    #pragma unroll
    for (int o = 32; o; o >>= 1) acc += __shfl_down(acc, o);
    if (lane == 0){
        float c = acc * inv_x[i] * inv_w[lab];
        c = fminf(fmaxf(c, -1.f), 1.f);
        tgt[i] = c;
    }
}

// ---- fused i8 GEMM: 256x256 tile, K-tile=128 i8, 2 phases/tile, NT=8 ----
#define BM 256
#define BN 256
#define BKB 128              // i8 elems (bytes) per K-tile
#define NT (DIM/BKB)         // 8
#define GRID_X (NCLS/BN)     // 40
#define GRID_Y (N_ROWS/BM)   // 32
#define NWG (GRID_X*GRID_Y)  // 1280, % 8 == 0

__global__ __launch_bounds__(512, 2) void gemm_kernel(
        const signed char* __restrict__ xq, const signed char* __restrict__ wq,
        const float* __restrict__ fx, const float* __restrict__ fw,
        float* __restrict__ gsum){
    __shared__ __align__(16) unsigned char As[2][BM*BKB];   // 2 x 32 KB
    __shared__ __align__(16) unsigned char Bs[2][BN*BKB];   // 2 x 32 KB
    __shared__ float sumrow[BM];

    int tid = threadIdx.x;
    int bid = blockIdx.x;
    // bijective XCD swizzle
    int swz = (bid & 7) * (NWG/8) + (bid >> 3);
    int by = swz / GRID_X, bx = swz % GRID_X;
    int row0 = by * BM, col0 = bx * BN;
    int wid = tid >> 6, lane = tid & 63;
    int wm = wid >> 2, wn = wid & 3;           // 2M x 4N wave grid; wave owns 128x64
    int g = lane >> 4, l16 = lane & 15;

    if (tid < BM) sumrow[tid] = 0.f;

    // staging geometry: one GLD16 = 512 thr x 16B = 64 rows x 128 B
    int srow = tid >> 3;                       // 0..63
    int csrc = (tid & 7) ^ (srow & 7);         // pre-swizzled source chunk (16B units)
    const signed char* gA = xq + (size_t)(row0 + srow) * DIM + csrc * 16;
    const signed char* gB = wq + (size_t)(col0 + srow) * DIM + csrc * 16;
    int ldso = srow * BKB + (tid & 7) * 16;    // linear LDS dest (bytes)

    i32x4 acc[8][4] = {};

    // prologue: stage tile 0 fully
    #pragma unroll
    for (int h = 0; h < 4; ++h){
        GLD16(gA + (size_t)(h*64)*DIM, &As[0][h*64*BKB + ldso]);
        GLD16(gB + (size_t)(h*64)*DIM, &Bs[0][h*64*BKB + ldso]);
    }
    asm volatile("s_waitcnt vmcnt(0)" ::: "memory");
    __builtin_amdgcn_s_barrier();

    for (int kt = 0; kt < NT; ++kt){
        int b = kt & 1, nb = b ^ 1;
        int knext = (kt + 1) * BKB;
        bool pre = (kt + 1 < NT);
        i32x4 af[8], bfv[4];

        // ---- P0: read ALL k0 fragments (A m0-7 + B n0-3, 12 ds_reads) ;
        //          stage next-tile A (4 GLDs) ; 32 MFMAs
        #pragma unroll
        for (int m = 0; m < 8; ++m){
            int r = wm*128 + m*16 + l16;
            af[m] = *(const i32x4*)&As[b][r*BKB + ((g ^ (r & 7)) << 4)];
        }
        #pragma unroll
        for (int n = 0; n < 4; ++n){
            int r = wn*64 + n*16 + l16;
            bfv[n] = *(const i32x4*)&Bs[b][r*BKB + ((g ^ (r & 7)) << 4)];
        }
        if (pre){
            GLD16(gA + knext,                    &As[nb][ldso]);
            GLD16(gA + knext + (size_t)64*DIM,   &As[nb][64*BKB + ldso]);
            GLD16(gA + knext + (size_t)128*DIM,  &As[nb][128*BKB + ldso]);
            GLD16(gA + knext + (size_t)192*DIM,  &As[nb][192*BKB + ldso]);
        }
        __builtin_amdgcn_s_barrier();
        asm volatile("s_waitcnt lgkmcnt(0)" ::: "memory");
        __builtin_amdgcn_sched_barrier(0);
        __builtin_amdgcn_s_setprio(1);
        #pragma unroll
        for (int m = 0; m < 8; ++m)
            #pragma unroll
            for (int n = 0; n < 4; ++n)
                acc[m][n] = __builtin_amdgcn_mfma_i32_16x16x64_i8(af[m], bfv[n], acc[m][n], 0, 0, 0);
        __builtin_amdgcn_s_setprio(0);
        __builtin_amdgcn_s_barrier();

        // ---- P1: read ALL k1 fragments ; stage next-tile B ; 32 MFMAs
        #pragma unroll
        for (int m = 0; m < 8; ++m){
            int r = wm*128 + m*16 + l16;
            af[m] = *(const i32x4*)&As[b][r*BKB + (((4+g) ^ (r & 7)) << 4)];
        }
        #pragma unroll
        for (int n = 0; n < 4; ++n){
            int r = wn*64 + n*16 + l16;
            bfv[n] = *(const i32x4*)&Bs[b][r*BKB + (((4+g) ^ (r & 7)) << 4)];
        }
        if (pre){
            GLD16(gB + knext,                    &Bs[nb][ldso]);
            GLD16(gB + knext + (size_t)64*DIM,   &Bs[nb][64*BKB + ldso]);
            GLD16(gB + knext + (size_t)128*DIM,  &Bs[nb][128*BKB + ldso]);
            GLD16(gB + knext + (size_t)192*DIM,  &Bs[nb][192*BKB + ldso]);
        }
        __builtin_amdgcn_s_barrier();
        asm volatile("s_waitcnt lgkmcnt(0)" ::: "memory");
        __builtin_amdgcn_sched_barrier(0);
        __builtin_amdgcn_s_setprio(1);
        #pragma unroll
        for (int m = 0; m < 8; ++m)
            #pragma unroll
            for (int n = 0; n < 4; ++n)
                acc[m][n] = __builtin_amdgcn_mfma_i32_16x16x64_i8(af[m], bfv[n], acc[m][n], 0, 0, 0);
        __builtin_amdgcn_s_setprio(0);

        // ---- K-tile boundary: A stages 1 phase old, B stages fresh (R4 pattern)
        asm volatile("s_waitcnt vmcnt(0)" ::: "memory");
        __builtin_amdgcn_sched_barrier(0);
        __builtin_amdgcn_s_barrier();
    }

    // epilogue: cosine = acc * fx[i] * fw[j]; clamp, exp(S*.), row-sum
    float fwv[4];
    #pragma unroll
    for (int n = 0; n < 4; ++n) fwv[n] = fw[col0 + wn*64 + n*16 + l16];
    #pragma unroll
    for (int m = 0; m < 8; ++m){
        #pragma unroll
        for (int rg = 0; rg < 4; ++rg){
            int rl = wm*128 + m*16 + g*4 + rg;       // local row of this value
            float fxr = fx[row0 + rl];
            float v = 0.f;
            #pragma unroll
            for (int n = 0; n < 4; ++n){
                float c = (float)acc[m][n][rg] * fxr * fwv[n];
                c = fminf(fmaxf(c, -1.f), 1.f);
                v += __expf(S_SCALE * c);
            }
            v += __shfl_xor(v, 1);
            v += __shfl_xor(v, 2);
            v += __shfl_xor(v, 4);
            v += __shfl_xor(v, 8);
            if (l16 == 0) atomicAdd(&sumrow[rl], v);
        }
    }
    __syncthreads();
    if (tid < BM) atomicAdd(&gsum[row0 + tid], sumrow[tid]);
}

// ---------------- finalize: per-row loss, mean (1024 threads) ----------------
__global__ void finalize_kernel(const float* __restrict__ tgt, const float* __restrict__ gsum,
                                const int* __restrict__ labels, float* __restrict__ out){
    double local = 0.0;
    for (int i = threadIdx.x; i < N_ROWS; i += 1024){
        float tv = tgt[i];
        float m  = (labels[i] <= 5) ? M_LARGE : M_SMALL;
        float numer = S_SCALE * (tv - m);
        float excl  = gsum[i] - __expf(S_SCALE * tv);
        float denom = __expf(numer) + excl;
        float L = numer - logf(denom);
        local += (double)L;
    }
    #pragma unroll
    for (int o = 32; o; o >>= 1) local += __shfl_down(local, o);
    __shared__ double part[16];
    int lane = threadIdx.x & 63, wid = threadIdx.x >> 6;
    if (lane == 0) part[wid] = local;
    __syncthreads();
    if (threadIdx.x == 0){
        double s = 0.0;
        #pragma unroll
        for (int p = 0; p < 16; ++p) s += part[p];
        out[0] = (float)(-s / (double)N_ROWS);
    }
}

extern "C" void kernel_launch(void* const* d_in, const int* in_sizes, int n_in,
                              void* d_out, int out_size, void* d_ws, size_t ws_size,
                              hipStream_t stream) {
    const float* x      = (const float*)d_in[0];
    const int*   labels = (const int*)  d_in[1];
    const float* w      = (const float*)d_in[2];

    float* ws    = (float*)d_ws;
    float* inv_x = ws;                    // N
    float* inv_w = inv_x + N_ROWS;        // C
    float* fx    = inv_w + NCLS;          // N
    float* fw    = fx    + N_ROWS;        // C
    float* tgt   = fw    + NCLS;          // N
    float* gsum  = tgt   + N_ROWS;        // N
    signed char* xq = (signed char*)(gsum + N_ROWS);   // N*D i8
    signed char* wq = xq + (size_t)N_ROWS * DIM;       // C*D i8

    prep_kernel<<<N_ROWS + NCLS, 256, 0, stream>>>(x, w, inv_x, inv_w, fx, fw, gsum, xq, wq);
    target_kernel<<<N_ROWS/4, 256, 0, stream>>>(x, w, labels, inv_x, inv_w, tgt);
    gemm_kernel<<<NWG, 512, 0, stream>>>(xq, wq, fx, fw, gsum);
    finalize_kernel<<<1, 1024, 0, stream>>>(tgt, gsum, labels, (float*)d_out);
}